// Round 5
// baseline (1044.683 us; speedup 1.0000x reference)
//
#include <hip/hip_runtime.h>
#include <hip/hip_bf16.h>

// TreeRNN: K=8, DEPTH=7, N=299593, V=32000, X=H=O=128.
// bf16 MFMA 16x16x32, fp32 accumulate.
// Structure: h never touches HBM. Each level computes the 8-child sums of
// its own h tile (in LDS for the W_out GEMM) and writes one bf16 "childsum"
// row per parent; the parent level loads its U-GEMM A-fragments straight
// from that row. Embed-GEMM A-fragments load directly from a pre-converted
// bf16 emb table. 16 rows per wave (r2's 32-row variant regressed: VGPR
// 48->172 halved occupancy on a latency-bound kernel).
// Levels 5..0 run in ONE kernel. r3/r4 failed with IDENTICAL absmax ->
// hipLaunchCooperativeKernel silently never ran under graph capture (not a
// coherence bug). This round: regular <<<512,256>>> launch + hand-rolled
// single-use grid barrier (device-scope atomicAdd + acquire spin; counters
// zeroed by prep each launch since the harness re-poisons d_ws).
// Co-residency: __launch_bounds__(256,4) caps 128 VGPR -> >=4 blocks/CU
// capacity (1024) vs 512 launched, 2x margin. All intra-dispatch cs
// read/writes are agent-scope (sc1) atomics bypassing the non-coherent
// per-XCD L2s, so correctness does not depend on fence lowering.
// out stores are non-temporal (153 MB write-once, keeps emb/cs cache-hot).
// Alignment fact: s_l - 1 = 8*s_{l-1}, so every 64-row block is exactly
// the children of 8 consecutive parents.

typedef __bf16 bf16x8 __attribute__((ext_vector_type(8)));
typedef float f32x4 __attribute__((ext_vector_type(4)));
typedef float f32x2 __attribute__((ext_vector_type(2)));
typedef unsigned short ushort8 __attribute__((ext_vector_type(8)));
typedef unsigned int uint2v __attribute__((ext_vector_type(2)));

#define NNODES 299593
#define NPAR   37449   // nodes 0..37448 have children
#define NBLK_UPPER 512

static __device__ __forceinline__ unsigned short f2bf(float f) {
  union { float f; unsigned int u; } v; v.f = f;
  unsigned int u = v.u;
  u += 0x7fff + ((u >> 16) & 1);   // RNE
  return (unsigned short)(u >> 16);
}

// pack 2 floats -> 2 bf16 in one dword (a -> low, b -> high)
static __device__ __forceinline__ unsigned int pk2bf(float a, float b) {
#if __has_builtin(__builtin_amdgcn_cvt_pk_bf16_f32)
  typedef __bf16 bf16x2 __attribute__((ext_vector_type(2)));
  union { bf16x2 v; unsigned int u; } c;
  c.v = __builtin_amdgcn_cvt_pk_bf16_f32(a, b);
  return c.u;
#else
  return (unsigned int)f2bf(a) | ((unsigned int)f2bf(b) << 16);
#endif
}

// tanh(x) = 1 - 2/(1+e^{2x})
static __device__ __forceinline__ float fast_tanh(float x) {
  float y = x * 2.885390081777927f;  // 2*log2(e)
#if __has_builtin(__builtin_amdgcn_exp2f)
  float e = __builtin_amdgcn_exp2f(y);
#else
  float e = __builtin_exp2f(y);
#endif
#if __has_builtin(__builtin_amdgcn_rcpf)
  float r = __builtin_amdgcn_rcpf(e + 1.0f);
#else
  float r = 1.0f / (e + 1.0f);
#endif
  return __builtin_fmaf(-2.0f, r, 1.0f);
}

// Swizzle W (128x128 row-major fp32) into B-fragment order for
// v_mfma_f32_16x16x32_bf16: frag f = ((kt*8+nt)*64 + lane)*8 + j
// holds W[kt*32 + (lane>>4)*8 + j][nt*16 + (lane&15)].
// Also converts emb (32000x128 fp32) -> bf16 once, and zeroes the grid
// barrier counters (d_ws is poison-filled by the harness every iteration).
__global__ __launch_bounds__(256) void prep_kernel(
    const float* __restrict__ W_in, const float* __restrict__ U,
    const float* __restrict__ W_out, const float* __restrict__ emb,
    unsigned short* __restrict__ w_sw, unsigned short* __restrict__ emb_bf,
    unsigned int* __restrict__ bar) {
  int t = blockIdx.x * 256 + threadIdx.x;
  if (t < 8)
    __hip_atomic_store(bar + t, 0u, __ATOMIC_RELAXED,
                       __HIP_MEMORY_SCOPE_AGENT);
  if (blockIdx.x < 192) {              // 49152 weight elements
    int f = t;
    int m = f >> 14;
    int r = f & 16383;
    int j = r & 7;
    int lane = (r >> 3) & 63;
    int nt = (r >> 9) & 7;
    int kt = (r >> 12) & 3;
    int k = kt * 32 + ((lane >> 4) * 8) + j;
    int n = nt * 16 + (lane & 15);
    const float* W = (m == 0) ? W_in : (m == 1) ? U : W_out;
    w_sw[f] = f2bf(W[k * 128 + n]);
  } else {                              // 4,096,000 emb elements, 8 per thread
    size_t i = (size_t)(t - 49152) * 8;
    f32x4 v0 = *(const f32x4*)(emb + i);
    f32x4 v1 = *(const f32x4*)(emb + i + 4);
    union { ushort8 s; unsigned int u[4]; } w;
    w.u[0] = pk2bf(v0[0], v0[1]);
    w.u[1] = pk2bf(v0[2], v0[3]);
    w.u[2] = pk2bf(v1[0], v1[1]);
    w.u[3] = pk2bf(v1[2], v1[3]);
    *(ushort8*)(emb_bf + i) = w.s;
  }
}

// load a 16B bf16 A-fragment, zeroed when !nz (per-lane predicate)
static __device__ __forceinline__ bf16x8 ldz(const unsigned short* p, int nz) {
  union { bf16x8 b; unsigned int u[4]; } v;
  v.b = *(const bf16x8*)p;
  if (!nz) { v.u[0] = 0; v.u[1] = 0; v.u[2] = 0; v.u[3] = 0; }
  return v.b;
}

// agent-scope (cross-XCD safe) variant: sc1 dword loads bypassing the
// reader's per-XCD L2 — for cs rows written earlier IN THIS dispatch
static __device__ __forceinline__ bf16x8 ldz_agent(const unsigned short* p,
                                                   int nz) {
  union { bf16x8 b; unsigned int u[4]; } v;
  const unsigned int* q = (const unsigned int*)p;
  v.u[0] = __hip_atomic_load(q + 0, __ATOMIC_RELAXED, __HIP_MEMORY_SCOPE_AGENT);
  v.u[1] = __hip_atomic_load(q + 1, __ATOMIC_RELAXED, __HIP_MEMORY_SCOPE_AGENT);
  v.u[2] = __hip_atomic_load(q + 2, __ATOMIC_RELAXED, __HIP_MEMORY_SCOPE_AGENT);
  v.u[3] = __hip_atomic_load(q + 3, __ATOMIC_RELAXED, __HIP_MEMORY_SCOPE_AGENT);
  if (!nz) { v.u[0] = 0; v.u[1] = 0; v.u[2] = 0; v.u[3] = 0; }
  return v.b;
}

// one K-block (kt) of a 16x128 MFMA row: 8 nt tiles, B frags from
// pre-swizzled global (L1/L2-resident, 32 KB/matrix)
static __device__ __forceinline__ void mfma_row8(f32x4 acc[8], bf16x8 a,
    const unsigned short* __restrict__ bkt, int lane) {
#pragma unroll
  for (int nt = 0; nt < 8; ++nt) {
    bf16x8 b = *(const bf16x8*)(bkt + nt * 512 + lane * 8);
    acc[nt] = __builtin_amdgcn_mfma_f32_16x16x32_bf16(a, b, acc[nt], 0, 0, 0);
  }
}

// CS_LD_AGENT / CS_ST_AGENT: sc1 agent-scope cs ops when producer/consumer
// are in the SAME dispatch (per-XCD L2s are not cross-coherent).
template <bool LEAF, bool CS_LD_AGENT, bool CS_ST_AGENT>
static __device__ __forceinline__ void tile_body(
    const int* __restrict__ x, const int* __restrict__ mask,
    const unsigned short* __restrict__ emb_bf,
    const float* __restrict__ b_in, const float* __restrict__ b_out,
    const unsigned short* __restrict__ w_sw,
    unsigned short* __restrict__ cs, float* __restrict__ out,
    int e, int row0, unsigned short (*Abuf)[136], int tid) {
  const int lane = tid & 63;
  const int wave = tid >> 6;
  const int coll = lane & 15;
  const int quad = lane >> 4;

  // per-lane A-row (row = coll of this wave's 16-row tile)
  const int garow = row0 + wave * 16 + coll;
  const int valid = garow < e;
  const int m = valid ? mask[garow] : 0;
  const int idx = valid ? x[garow] * m : 0;

  // ---- issue all A-fragment loads up front (hide gather latency) ----
  const unsigned short* arow = emb_bf + (size_t)idx * 128 + quad * 8;
  bf16x8 ea0 = ldz(arow, m);
  bf16x8 ea1 = ldz(arow + 32, m);
  bf16x8 ea2 = ldz(arow + 64, m);
  bf16x8 ea3 = ldz(arow + 96, m);
  bf16x8 ca0, ca1, ca2, ca3;
  if (!LEAF) {
    // childsum row of THIS node, produced by the child level.
    // garow may exceed e for partial tiles but stays < NPAR; ldz zeroes.
    const unsigned short* crow = cs + (size_t)garow * 128 + quad * 8;
    if constexpr (CS_LD_AGENT) {
      ca0 = ldz_agent(crow, valid);
      ca1 = ldz_agent(crow + 32, valid);
      ca2 = ldz_agent(crow + 64, valid);
      ca3 = ldz_agent(crow + 96, valid);
    } else {
      ca0 = ldz(crow, valid);
      ca1 = ldz(crow + 32, valid);
      ca2 = ldz(crow + 64, valid);
      ca3 = ldz(crow + 96, valid);
    }
  }

  f32x4 acc[8];
#pragma unroll
  for (int nt = 0; nt < 8; ++nt) acc[nt] = (f32x4){0.f, 0.f, 0.f, 0.f};

  // ---- GEMM 1: emb @ W_in ----
  mfma_row8(acc, ea0, w_sw, lane);
  mfma_row8(acc, ea1, w_sw + 4096, lane);
  mfma_row8(acc, ea2, w_sw + 8192, lane);
  mfma_row8(acc, ea3, w_sw + 12288, lane);

  // ---- GEMM 2: childsum @ U (accumulates into same acc) ----
  if (!LEAF) {
    mfma_row8(acc, ca0, w_sw + 16384, lane);
    mfma_row8(acc, ca1, w_sw + 20480, lane);
    mfma_row8(acc, ca2, w_sw + 24576, lane);
    mfma_row8(acc, ca3, w_sw + 28672, lane);
  }

  // ---- epilogue 1: + m*b_in, fast tanh; h -> LDS (wave-private) ----
  float binv[8];
#pragma unroll
  for (int nt = 0; nt < 8; ++nt) binv[nt] = b_in[nt * 16 + coll];
#pragma unroll
  for (int r2 = 0; r2 < 4; ++r2) {
    const int rowl = wave * 16 + quad * 4 + r2;  // C layout: row=quad*4+reg
    const int grow = row0 + rowl;
    const float mval = (grow < e) ? (float)mask[grow] : 0.f;
#pragma unroll
    for (int nt = 0; nt < 8; ++nt) {
      float t = acc[nt][r2] + mval * binv[nt];
      Abuf[rowl][nt * 16 + coll] = f2bf(fast_tanh(t));
    }
  }
  __builtin_amdgcn_wave_barrier();

  // ---- childsum production: wave's 16 rows = 2 complete parents ----
  // (row0-1 is divisible by 8 for every level; root tile row0==0 skips)
  if (row0 > 0) {
    const int j = lane >> 5;              // parent 0/1 within wave
    const int c4 = (lane & 31) * 4;       // ushort col 0,4,...,124
    const int childrow0 = row0 + (wave * 2 + j) * 8;
    if (childrow0 < e) {
      const int lr0 = wave * 16 + j * 8;
      f32x2 sA = {0.f, 0.f}, sB = {0.f, 0.f};
#pragma unroll
      for (int r = 0; r < 8; ++r) {       // children ascending: same fp32
        const unsigned int* pr =          // summation order as before
            (const unsigned int*)&Abuf[lr0 + r][c4];
        unsigned int u0 = pr[0], u1 = pr[1];
        union { unsigned int u; float f; } l0, h0, l1, h1;
        l0.u = u0 << 16; h0.u = u0 & 0xffff0000u;
        l1.u = u1 << 16; h1.u = u1 & 0xffff0000u;
        sA += (f32x2){l0.f, h0.f};
        sB += (f32x2){l1.f, h1.f};
      }
      const int p = ((row0 - 1) >> 3) + wave * 2 + j;
      unsigned int wx = pk2bf(sA[0], sA[1]);
      unsigned int wy = pk2bf(sB[0], sB[1]);
      if constexpr (CS_ST_AGENT) {
        unsigned int* q = (unsigned int*)(cs + (size_t)p * 128 + c4);
        __hip_atomic_store(q, wx, __ATOMIC_RELAXED, __HIP_MEMORY_SCOPE_AGENT);
        __hip_atomic_store(q + 1, wy, __ATOMIC_RELAXED,
                           __HIP_MEMORY_SCOPE_AGENT);
      } else {
        uint2v w; w.x = wx; w.y = wy;
        *(uint2v*)(cs + (size_t)p * 128 + c4) = w;
      }
    }
  }

  // ---- GEMM 3: out = h @ W_out + b_out (A frags transposed via LDS) ----
  f32x4 oacc[8];
#pragma unroll
  for (int nt = 0; nt < 8; ++nt) oacc[nt] = (f32x4){0.f, 0.f, 0.f, 0.f};
  const unsigned short* ab = &Abuf[wave * 16][0] + coll * 136 + quad * 8;
#pragma unroll
  for (int kt = 0; kt < 4; ++kt) {
    bf16x8 a = *(const bf16x8*)(ab + kt * 32);
    mfma_row8(oacc, a, w_sw + 32768 + kt * 4096, lane);
  }

  float boutv[8];
#pragma unroll
  for (int nt = 0; nt < 8; ++nt) boutv[nt] = b_out[nt * 16 + coll];
#pragma unroll
  for (int r2 = 0; r2 < 4; ++r2) {
    const int rowl = wave * 16 + quad * 4 + r2;
    const int grow = row0 + rowl;
    if (grow < e) {
#pragma unroll
      for (int nt = 0; nt < 8; ++nt)
        __builtin_nontemporal_store(oacc[nt][r2] + boutv[nt],
                                    &out[(size_t)grow * 128 + nt * 16 + coll]);
    }
  }
}

// Single-use grid barrier: each launch re-zeroes counters in prep_kernel.
// ACQ_REL add releases this block's prior (agent-scope) stores; acquire
// spin load + agent-scope data reads make post-barrier reads safe.
static __device__ __forceinline__ void grid_barrier(unsigned int* ctr,
                                                    int tid) {
  __syncthreads();                       // block's waves done (vmem drained
  if (tid == 0) {                        // by the release atomic below)
    __hip_atomic_fetch_add(ctr, 1u, __ATOMIC_ACQ_REL,
                           __HIP_MEMORY_SCOPE_AGENT);
    while (__hip_atomic_load(ctr, __ATOMIC_ACQUIRE,
                             __HIP_MEMORY_SCOPE_AGENT) < (unsigned)NBLK_UPPER)
      __builtin_amdgcn_s_sleep(4);
  }
  __syncthreads();                       // release all waves
}

// Leaf level: full-TLP regular launch (4096 blocks). cs write consumed next
// dispatch -> plain stores (kernel-end release flushes L2).
__global__ __launch_bounds__(256) void leaf_kernel(
    const int* __restrict__ x, const int* __restrict__ mask,
    const unsigned short* __restrict__ emb_bf, const float* __restrict__ b_in,
    const float* __restrict__ b_out, const unsigned short* __restrict__ w_sw,
    unsigned short* __restrict__ cs, float* __restrict__ out) {
  __shared__ __align__(16) unsigned short Abuf[64][136];
  tile_body<true, false, false>(x, mask, emb_bf, b_in, b_out, w_sw, cs, out,
                                299593, 37449 + blockIdx.x * 64, Abuf,
                                threadIdx.x);
}

// Levels 5..0, one REGULAR dispatch, 512 blocks, manual grid barriers.
// launch_bounds(256,4): <=128 VGPR -> >=4 blocks/CU capacity (1024 blocks)
// vs 512 launched: co-residency guaranteed with 2x margin (no deadlock).
__global__ __launch_bounds__(256, 4) void upper_kernel(
    const int* __restrict__ x, const int* __restrict__ mask,
    const unsigned short* __restrict__ emb_bf, const float* __restrict__ b_in,
    const float* __restrict__ b_out, const unsigned short* __restrict__ w_sw,
    unsigned short* __restrict__ cs, float* __restrict__ out,
    unsigned int* __restrict__ bar) {
  __shared__ __align__(16) unsigned short Abuf[64][136];
  const int bid = blockIdx.x;
  const int tid = threadIdx.x;

  // l=5: rows 4681..37448, 512 blocks (cs read is leaf's, cross-dispatch,
  // but agent reads are used uniformly — they bypass only the reader L2)
  tile_body<false, true, true>(x, mask, emb_bf, b_in, b_out, w_sw, cs, out,
                               37449, 4681 + bid * 64, Abuf, tid);
  grid_barrier(bar + 0, tid);
  // l=4: rows 585..4680, 64 blocks
  if (bid < 64)
    tile_body<false, true, true>(x, mask, emb_bf, b_in, b_out, w_sw, cs, out,
                                 4681, 585 + bid * 64, Abuf, tid);
  grid_barrier(bar + 1, tid);
  // l=3: rows 73..584, 8 blocks
  if (bid < 8)
    tile_body<false, true, true>(x, mask, emb_bf, b_in, b_out, w_sw, cs, out,
                                 585, 73 + bid * 64, Abuf, tid);
  grid_barrier(bar + 2, tid);
  // l=2: rows 9..72 (one 64-row tile)
  if (bid == 0)
    tile_body<false, true, true>(x, mask, emb_bf, b_in, b_out, w_sw, cs, out,
                                 73, 9, Abuf, tid);
  grid_barrier(bar + 3, tid);
  // l=1: rows 1..8
  if (bid == 0)
    tile_body<false, true, true>(x, mask, emb_bf, b_in, b_out, w_sw, cs, out,
                                 9, 1, Abuf, tid);
  grid_barrier(bar + 4, tid);
  // l=0: row 0 (row0==0 -> no cs store)
  if (bid == 0)
    tile_body<false, true, true>(x, mask, emb_bf, b_in, b_out, w_sw, cs, out,
                                 1, 0, Abuf, tid);
}

extern "C" void kernel_launch(void* const* d_in, const int* in_sizes, int n_in,
                              void* d_out, int out_size, void* d_ws,
                              size_t ws_size, hipStream_t stream) {
  const int* x = (const int*)d_in[0];
  const int* mask = (const int*)d_in[1];
  // d_in[2] = children: implied (child rows of i are i*8+1..i*8+8)
  const float* emb = (const float*)d_in[3];
  const float* W_in = (const float*)d_in[4];
  const float* b_in = (const float*)d_in[5];
  const float* U = (const float*)d_in[6];
  const float* W_out = (const float*)d_in[7];
  const float* b_out = (const float*)d_in[8];
  float* out = (float*)d_out;

  // ws layout: emb bf16 [32000*128] | childsum bf16 [NPAR*128] |
  //            w_sw [3*16384] | barrier counters [8 u32]
  unsigned short* emb_bf = (unsigned short*)d_ws;
  unsigned short* cs = emb_bf + (size_t)32000 * 128;
  unsigned short* w_sw = cs + (size_t)NPAR * 128;
  unsigned int* bar = (unsigned int*)(w_sw + 49152);

  prep_kernel<<<2192, 256, 0, stream>>>(W_in, U, W_out, emb, w_sw, emb_bf,
                                        bar);

  // leaf level l=6: rows 37449..299592 -> childsum for parents 4681..37448
  leaf_kernel<<<4096, 256, 0, stream>>>(x, mask, emb_bf, b_in, b_out, w_sw,
                                        cs, out);

  // levels 5..0 in one regular dispatch with manual grid barriers
  upper_kernel<<<NBLK_UPPER, 256, 0, stream>>>(x, mask, emb_bf, b_in, b_out,
                                               w_sw, cs, out, bar);
}

// Round 6
// 409.478 us; speedup vs baseline: 2.5513x; 2.5513x over previous
//
#include <hip/hip_runtime.h>
#include <hip/hip_bf16.h>

// TreeRNN: K=8, DEPTH=7, N=299593, V=32000, X=H=O=128.
// bf16 MFMA 16x16x32, fp32 accumulate.
// Structure: h never touches HBM. Each level computes the 8-child sums of
// its own h tile (in LDS for the W_out GEMM) and writes one bf16 "childsum"
// row per parent; the parent level loads its U-GEMM A-fragments straight
// from that row. Embed-GEMM A-fragments load directly from a pre-converted
// bf16 emb table. 16 rows per wave.
// Levels 5..0 in ONE regular <<<512,256>>> dispatch with a hand-rolled grid
// barrier. r5 PASSED but the barrier cost ~170us each: ACQ_REL/ACQUIRE agent
// atomics lower to per-op cache writeback/invalidate; 512 spinners of
// cache-maintenance ops serialized the chip. This round: RELAXED fetch_add +
// RELAXED spin load + s_sleep backoff. Safe because all intra-dispatch cs
// data ops are already agent-scope sc1 (coherence-point direct) and
// __syncthreads' vmcnt(0) drain orders them before the counter increment.
// Also: l5's cs reads revert to plain cached loads (producer is the leaf
// DISPATCH -> cross-dispatch RAW, r1-proven; keeps the 8.4 MB read in L2).
// Co-residency: __launch_bounds__(256,4) -> >=4 blocks/CU capacity (1024)
// vs 512 launched (r5 empirically confirmed: completed, no deadlock).
// out stores non-temporal (153 MB write-once).
// Alignment fact: s_l - 1 = 8*s_{l-1}, so every 64-row block is exactly
// the children of 8 consecutive parents.

typedef __bf16 bf16x8 __attribute__((ext_vector_type(8)));
typedef float f32x4 __attribute__((ext_vector_type(4)));
typedef float f32x2 __attribute__((ext_vector_type(2)));
typedef unsigned short ushort8 __attribute__((ext_vector_type(8)));
typedef unsigned int uint2v __attribute__((ext_vector_type(2)));

#define NNODES 299593
#define NPAR   37449   // nodes 0..37448 have children
#define NBLK_UPPER 512

static __device__ __forceinline__ unsigned short f2bf(float f) {
  union { float f; unsigned int u; } v; v.f = f;
  unsigned int u = v.u;
  u += 0x7fff + ((u >> 16) & 1);   // RNE
  return (unsigned short)(u >> 16);
}

// pack 2 floats -> 2 bf16 in one dword (a -> low, b -> high)
static __device__ __forceinline__ unsigned int pk2bf(float a, float b) {
#if __has_builtin(__builtin_amdgcn_cvt_pk_bf16_f32)
  typedef __bf16 bf16x2 __attribute__((ext_vector_type(2)));
  union { bf16x2 v; unsigned int u; } c;
  c.v = __builtin_amdgcn_cvt_pk_bf16_f32(a, b);
  return c.u;
#else
  return (unsigned int)f2bf(a) | ((unsigned int)f2bf(b) << 16);
#endif
}

// tanh(x) = 1 - 2/(1+e^{2x})
static __device__ __forceinline__ float fast_tanh(float x) {
  float y = x * 2.885390081777927f;  // 2*log2(e)
#if __has_builtin(__builtin_amdgcn_exp2f)
  float e = __builtin_amdgcn_exp2f(y);
#else
  float e = __builtin_exp2f(y);
#endif
#if __has_builtin(__builtin_amdgcn_rcpf)
  float r = __builtin_amdgcn_rcpf(e + 1.0f);
#else
  float r = 1.0f / (e + 1.0f);
#endif
  return __builtin_fmaf(-2.0f, r, 1.0f);
}

// Swizzle W (128x128 row-major fp32) into B-fragment order for
// v_mfma_f32_16x16x32_bf16: frag f = ((kt*8+nt)*64 + lane)*8 + j
// holds W[kt*32 + (lane>>4)*8 + j][nt*16 + (lane&15)].
// Also converts emb (32000x128 fp32) -> bf16 once, and zeroes the grid
// barrier counters (d_ws is poison-filled by the harness every iteration).
__global__ __launch_bounds__(256) void prep_kernel(
    const float* __restrict__ W_in, const float* __restrict__ U,
    const float* __restrict__ W_out, const float* __restrict__ emb,
    unsigned short* __restrict__ w_sw, unsigned short* __restrict__ emb_bf,
    unsigned int* __restrict__ bar) {
  int t = blockIdx.x * 256 + threadIdx.x;
  if (t < 8)
    __hip_atomic_store(bar + t, 0u, __ATOMIC_RELAXED,
                       __HIP_MEMORY_SCOPE_AGENT);
  if (blockIdx.x < 192) {              // 49152 weight elements
    int f = t;
    int m = f >> 14;
    int r = f & 16383;
    int j = r & 7;
    int lane = (r >> 3) & 63;
    int nt = (r >> 9) & 7;
    int kt = (r >> 12) & 3;
    int k = kt * 32 + ((lane >> 4) * 8) + j;
    int n = nt * 16 + (lane & 15);
    const float* W = (m == 0) ? W_in : (m == 1) ? U : W_out;
    w_sw[f] = f2bf(W[k * 128 + n]);
  } else {                              // 4,096,000 emb elements, 8 per thread
    size_t i = (size_t)(t - 49152) * 8;
    f32x4 v0 = *(const f32x4*)(emb + i);
    f32x4 v1 = *(const f32x4*)(emb + i + 4);
    union { ushort8 s; unsigned int u[4]; } w;
    w.u[0] = pk2bf(v0[0], v0[1]);
    w.u[1] = pk2bf(v0[2], v0[3]);
    w.u[2] = pk2bf(v1[0], v1[1]);
    w.u[3] = pk2bf(v1[2], v1[3]);
    *(ushort8*)(emb_bf + i) = w.s;
  }
}

// load a 16B bf16 A-fragment, zeroed when !nz (per-lane predicate)
static __device__ __forceinline__ bf16x8 ldz(const unsigned short* p, int nz) {
  union { bf16x8 b; unsigned int u[4]; } v;
  v.b = *(const bf16x8*)p;
  if (!nz) { v.u[0] = 0; v.u[1] = 0; v.u[2] = 0; v.u[3] = 0; }
  return v.b;
}

// agent-scope (cross-XCD safe) variant: sc1 dword loads bypassing the
// reader's per-XCD L2 — for cs rows written earlier IN THIS dispatch
static __device__ __forceinline__ bf16x8 ldz_agent(const unsigned short* p,
                                                   int nz) {
  union { bf16x8 b; unsigned int u[4]; } v;
  const unsigned int* q = (const unsigned int*)p;
  v.u[0] = __hip_atomic_load(q + 0, __ATOMIC_RELAXED, __HIP_MEMORY_SCOPE_AGENT);
  v.u[1] = __hip_atomic_load(q + 1, __ATOMIC_RELAXED, __HIP_MEMORY_SCOPE_AGENT);
  v.u[2] = __hip_atomic_load(q + 2, __ATOMIC_RELAXED, __HIP_MEMORY_SCOPE_AGENT);
  v.u[3] = __hip_atomic_load(q + 3, __ATOMIC_RELAXED, __HIP_MEMORY_SCOPE_AGENT);
  if (!nz) { v.u[0] = 0; v.u[1] = 0; v.u[2] = 0; v.u[3] = 0; }
  return v.b;
}

// one K-block (kt) of a 16x128 MFMA row: 8 nt tiles, B frags from
// pre-swizzled global (L1/L2-resident, 32 KB/matrix)
static __device__ __forceinline__ void mfma_row8(f32x4 acc[8], bf16x8 a,
    const unsigned short* __restrict__ bkt, int lane) {
#pragma unroll
  for (int nt = 0; nt < 8; ++nt) {
    bf16x8 b = *(const bf16x8*)(bkt + nt * 512 + lane * 8);
    acc[nt] = __builtin_amdgcn_mfma_f32_16x16x32_bf16(a, b, acc[nt], 0, 0, 0);
  }
}

// CS_LD_AGENT / CS_ST_AGENT: sc1 agent-scope cs ops when producer/consumer
// are in the SAME dispatch (per-XCD L2s are not cross-coherent).
template <bool LEAF, bool CS_LD_AGENT, bool CS_ST_AGENT>
static __device__ __forceinline__ void tile_body(
    const int* __restrict__ x, const int* __restrict__ mask,
    const unsigned short* __restrict__ emb_bf,
    const float* __restrict__ b_in, const float* __restrict__ b_out,
    const unsigned short* __restrict__ w_sw,
    unsigned short* __restrict__ cs, float* __restrict__ out,
    int e, int row0, unsigned short (*Abuf)[136], int tid) {
  const int lane = tid & 63;
  const int wave = tid >> 6;
  const int coll = lane & 15;
  const int quad = lane >> 4;

  // per-lane A-row (row = coll of this wave's 16-row tile)
  const int garow = row0 + wave * 16 + coll;
  const int valid = garow < e;
  const int m = valid ? mask[garow] : 0;
  const int idx = valid ? x[garow] * m : 0;

  // ---- issue all A-fragment loads up front (hide gather latency) ----
  const unsigned short* arow = emb_bf + (size_t)idx * 128 + quad * 8;
  bf16x8 ea0 = ldz(arow, m);
  bf16x8 ea1 = ldz(arow + 32, m);
  bf16x8 ea2 = ldz(arow + 64, m);
  bf16x8 ea3 = ldz(arow + 96, m);
  bf16x8 ca0, ca1, ca2, ca3;
  if (!LEAF) {
    // childsum row of THIS node, produced by the child level.
    // garow may exceed e for partial tiles but stays < NPAR; ldz zeroes.
    const unsigned short* crow = cs + (size_t)garow * 128 + quad * 8;
    if constexpr (CS_LD_AGENT) {
      ca0 = ldz_agent(crow, valid);
      ca1 = ldz_agent(crow + 32, valid);
      ca2 = ldz_agent(crow + 64, valid);
      ca3 = ldz_agent(crow + 96, valid);
    } else {
      ca0 = ldz(crow, valid);
      ca1 = ldz(crow + 32, valid);
      ca2 = ldz(crow + 64, valid);
      ca3 = ldz(crow + 96, valid);
    }
  }

  f32x4 acc[8];
#pragma unroll
  for (int nt = 0; nt < 8; ++nt) acc[nt] = (f32x4){0.f, 0.f, 0.f, 0.f};

  // ---- GEMM 1: emb @ W_in ----
  mfma_row8(acc, ea0, w_sw, lane);
  mfma_row8(acc, ea1, w_sw + 4096, lane);
  mfma_row8(acc, ea2, w_sw + 8192, lane);
  mfma_row8(acc, ea3, w_sw + 12288, lane);

  // ---- GEMM 2: childsum @ U (accumulates into same acc) ----
  if (!LEAF) {
    mfma_row8(acc, ca0, w_sw + 16384, lane);
    mfma_row8(acc, ca1, w_sw + 20480, lane);
    mfma_row8(acc, ca2, w_sw + 24576, lane);
    mfma_row8(acc, ca3, w_sw + 28672, lane);
  }

  // ---- epilogue 1: + m*b_in, fast tanh; h -> LDS (wave-private) ----
  float binv[8];
#pragma unroll
  for (int nt = 0; nt < 8; ++nt) binv[nt] = b_in[nt * 16 + coll];
#pragma unroll
  for (int r2 = 0; r2 < 4; ++r2) {
    const int rowl = wave * 16 + quad * 4 + r2;  // C layout: row=quad*4+reg
    const int grow = row0 + rowl;
    const float mval = (grow < e) ? (float)mask[grow] : 0.f;
#pragma unroll
    for (int nt = 0; nt < 8; ++nt) {
      float t = acc[nt][r2] + mval * binv[nt];
      Abuf[rowl][nt * 16 + coll] = f2bf(fast_tanh(t));
    }
  }
  __builtin_amdgcn_wave_barrier();

  // ---- childsum production: wave's 16 rows = 2 complete parents ----
  // (row0-1 is divisible by 8 for every level; root tile row0==0 skips)
  if (row0 > 0) {
    const int j = lane >> 5;              // parent 0/1 within wave
    const int c4 = (lane & 31) * 4;       // ushort col 0,4,...,124
    const int childrow0 = row0 + (wave * 2 + j) * 8;
    if (childrow0 < e) {
      const int lr0 = wave * 16 + j * 8;
      f32x2 sA = {0.f, 0.f}, sB = {0.f, 0.f};
#pragma unroll
      for (int r = 0; r < 8; ++r) {       // children ascending: same fp32
        const unsigned int* pr =          // summation order as before
            (const unsigned int*)&Abuf[lr0 + r][c4];
        unsigned int u0 = pr[0], u1 = pr[1];
        union { unsigned int u; float f; } l0, h0, l1, h1;
        l0.u = u0 << 16; h0.u = u0 & 0xffff0000u;
        l1.u = u1 << 16; h1.u = u1 & 0xffff0000u;
        sA += (f32x2){l0.f, h0.f};
        sB += (f32x2){l1.f, h1.f};
      }
      const int p = ((row0 - 1) >> 3) + wave * 2 + j;
      unsigned int wx = pk2bf(sA[0], sA[1]);
      unsigned int wy = pk2bf(sB[0], sB[1]);
      if constexpr (CS_ST_AGENT) {
        unsigned int* q = (unsigned int*)(cs + (size_t)p * 128 + c4);
        __hip_atomic_store(q, wx, __ATOMIC_RELAXED, __HIP_MEMORY_SCOPE_AGENT);
        __hip_atomic_store(q + 1, wy, __ATOMIC_RELAXED,
                           __HIP_MEMORY_SCOPE_AGENT);
      } else {
        uint2v w; w.x = wx; w.y = wy;
        *(uint2v*)(cs + (size_t)p * 128 + c4) = w;
      }
    }
  }

  // ---- GEMM 3: out = h @ W_out + b_out (A frags transposed via LDS) ----
  f32x4 oacc[8];
#pragma unroll
  for (int nt = 0; nt < 8; ++nt) oacc[nt] = (f32x4){0.f, 0.f, 0.f, 0.f};
  const unsigned short* ab = &Abuf[wave * 16][0] + coll * 136 + quad * 8;
#pragma unroll
  for (int kt = 0; kt < 4; ++kt) {
    bf16x8 a = *(const bf16x8*)(ab + kt * 32);
    mfma_row8(oacc, a, w_sw + 32768 + kt * 4096, lane);
  }

  float boutv[8];
#pragma unroll
  for (int nt = 0; nt < 8; ++nt) boutv[nt] = b_out[nt * 16 + coll];
#pragma unroll
  for (int r2 = 0; r2 < 4; ++r2) {
    const int rowl = wave * 16 + quad * 4 + r2;
    const int grow = row0 + rowl;
    if (grow < e) {
#pragma unroll
      for (int nt = 0; nt < 8; ++nt)
        __builtin_nontemporal_store(oacc[nt][r2] + boutv[nt],
                                    &out[(size_t)grow * 128 + nt * 16 + coll]);
    }
  }
}

// Relaxed single-use grid barrier. Data safety does NOT come from this
// barrier's ordering: cs stores are agent-scope sc1 (coherence-point
// direct) and __syncthreads' vmcnt(0) drain completes them before the
// increment. So both atomics are RELAXED (no per-op cache writeback /
// invalidate — the r5 slowness). s_sleep(32) (~2K clk) keeps the 512
// spinners' poll traffic negligible.
static __device__ __forceinline__ void grid_barrier(unsigned int* ctr,
                                                    int tid) {
  __syncthreads();
  if (tid == 0) {
    __hip_atomic_fetch_add(ctr, 1u, __ATOMIC_RELAXED,
                           __HIP_MEMORY_SCOPE_AGENT);
    while (__hip_atomic_load(ctr, __ATOMIC_RELAXED,
                             __HIP_MEMORY_SCOPE_AGENT) < (unsigned)NBLK_UPPER)
      __builtin_amdgcn_s_sleep(32);
  }
  __syncthreads();
}

// Leaf level: full-TLP regular launch (4096 blocks). cs write consumed next
// dispatch -> plain stores (kernel-end release flushes L2).
__global__ __launch_bounds__(256) void leaf_kernel(
    const int* __restrict__ x, const int* __restrict__ mask,
    const unsigned short* __restrict__ emb_bf, const float* __restrict__ b_in,
    const float* __restrict__ b_out, const unsigned short* __restrict__ w_sw,
    unsigned short* __restrict__ cs, float* __restrict__ out) {
  __shared__ __align__(16) unsigned short Abuf[64][136];
  tile_body<true, false, false>(x, mask, emb_bf, b_in, b_out, w_sw, cs, out,
                                299593, 37449 + blockIdx.x * 64, Abuf,
                                threadIdx.x);
}

// Levels 5..0, one REGULAR dispatch, 512 blocks, relaxed grid barriers.
// l5 reads leaf's cs (cross-dispatch -> plain cached loads, r1-proven) and
// writes agent-scope; l4..l0 read+write agent-scope (same-dispatch RAW).
__global__ __launch_bounds__(256, 4) void upper_kernel(
    const int* __restrict__ x, const int* __restrict__ mask,
    const unsigned short* __restrict__ emb_bf, const float* __restrict__ b_in,
    const float* __restrict__ b_out, const unsigned short* __restrict__ w_sw,
    unsigned short* __restrict__ cs, float* __restrict__ out,
    unsigned int* __restrict__ bar) {
  __shared__ __align__(16) unsigned short Abuf[64][136];
  const int bid = blockIdx.x;
  const int tid = threadIdx.x;

  // l=5: rows 4681..37448, 512 blocks
  tile_body<false, false, true>(x, mask, emb_bf, b_in, b_out, w_sw, cs, out,
                                37449, 4681 + bid * 64, Abuf, tid);
  grid_barrier(bar + 0, tid);
  // l=4: rows 585..4680, 64 blocks
  if (bid < 64)
    tile_body<false, true, true>(x, mask, emb_bf, b_in, b_out, w_sw, cs, out,
                                 4681, 585 + bid * 64, Abuf, tid);
  grid_barrier(bar + 1, tid);
  // l=3: rows 73..584, 8 blocks
  if (bid < 8)
    tile_body<false, true, true>(x, mask, emb_bf, b_in, b_out, w_sw, cs, out,
                                 585, 73 + bid * 64, Abuf, tid);
  grid_barrier(bar + 2, tid);
  // l=2: rows 9..72 (one 64-row tile)
  if (bid == 0)
    tile_body<false, true, true>(x, mask, emb_bf, b_in, b_out, w_sw, cs, out,
                                 73, 9, Abuf, tid);
  grid_barrier(bar + 3, tid);
  // l=1: rows 1..8
  if (bid == 0)
    tile_body<false, true, true>(x, mask, emb_bf, b_in, b_out, w_sw, cs, out,
                                 9, 1, Abuf, tid);
  grid_barrier(bar + 4, tid);
  // l=0: row 0 (row0==0 -> no cs store)
  if (bid == 0)
    tile_body<false, true, true>(x, mask, emb_bf, b_in, b_out, w_sw, cs, out,
                                 1, 0, Abuf, tid);
}

extern "C" void kernel_launch(void* const* d_in, const int* in_sizes, int n_in,
                              void* d_out, int out_size, void* d_ws,
                              size_t ws_size, hipStream_t stream) {
  const int* x = (const int*)d_in[0];
  const int* mask = (const int*)d_in[1];
  // d_in[2] = children: implied (child rows of i are i*8+1..i*8+8)
  const float* emb = (const float*)d_in[3];
  const float* W_in = (const float*)d_in[4];
  const float* b_in = (const float*)d_in[5];
  const float* U = (const float*)d_in[6];
  const float* W_out = (const float*)d_in[7];
  const float* b_out = (const float*)d_in[8];
  float* out = (float*)d_out;

  // ws layout: emb bf16 [32000*128] | childsum bf16 [NPAR*128] |
  //            w_sw [3*16384] | barrier counters [8 u32]
  unsigned short* emb_bf = (unsigned short*)d_ws;
  unsigned short* cs = emb_bf + (size_t)32000 * 128;
  unsigned short* w_sw = cs + (size_t)NPAR * 128;
  unsigned int* bar = (unsigned int*)(w_sw + 49152);

  prep_kernel<<<2192, 256, 0, stream>>>(W_in, U, W_out, emb, w_sw, emb_bf,
                                        bar);

  // leaf level l=6: rows 37449..299592 -> childsum for parents 4681..37448
  leaf_kernel<<<4096, 256, 0, stream>>>(x, mask, emb_bf, b_in, b_out, w_sw,
                                        cs, out);

  // levels 5..0 in one regular dispatch with relaxed grid barriers
  upper_kernel<<<NBLK_UPPER, 256, 0, stream>>>(x, mask, emb_bf, b_in, b_out,
                                               w_sw, cs, out, bar);
}

// Round 7
// 379.189 us; speedup vs baseline: 2.7550x; 1.0799x over previous
//
#include <hip/hip_runtime.h>
#include <hip/hip_bf16.h>

// TreeRNN: K=8, DEPTH=7, N=299593, V=32000, X=H=O=128.
// bf16 MFMA 16x16x32, fp32 accumulate.
// Structure: h never touches HBM. Each level computes the 8-child sums of
// its own h tile (in LDS for the W_out GEMM) and writes one bf16 "childsum"
// row per parent; the parent level loads its U-GEMM A-fragments straight
// from that row. Embed-GEMM A-fragments load directly from a pre-converted
// bf16 emb table. 16 rows per wave.
// Levels 5..0 in ONE regular <<<512,256>>> dispatch, 3 relaxed grid
// barriers (post l5/l4/l3); l2,l1,l0 chain inside block 0 via syncthreads.
// Coherence protocol (r3-r6 lessons):
//   - intra-dispatch cs WRITES: agent-scope sc1 stores (bypass the writer
//     XCD's non-coherent L2; plain stores strand dirty lines -> r3 fail).
//   - intra-dispatch cs READS: PLAIN cached loads. Safe: dispatch start
//     invalidates L2 (proven by r0/r1 cross-dispatch plain RAW through the
//     poisoned ws) and no cs line is plain-read before its sc1 write
//     (checked per level; tiles are exact-64 multiples except l1/l0 whose
//     overruns touch only already-consumed rows). r6's ldz_agent atomic
//     loads serialized (per-op waitcnt, no MLP) -> ~13us/level, the bulk
//     of its 174us.
//   - barrier: relaxed fetch_add + relaxed spin (r6: acq/rel cache
//     maintenance cost ~170us/barrier in r5).
// r6's nontemporal out stores reverted (only r6 leaf change; prefix time
// regressed ~85us vs r1 -> suspect; restore r1's proven plain stores).
// Alignment fact: s_l - 1 = 8*s_{l-1}, so every 64-row block is exactly
// the children of 8 consecutive parents.

typedef __bf16 bf16x8 __attribute__((ext_vector_type(8)));
typedef float f32x4 __attribute__((ext_vector_type(4)));
typedef float f32x2 __attribute__((ext_vector_type(2)));
typedef unsigned short ushort8 __attribute__((ext_vector_type(8)));
typedef unsigned int uint2v __attribute__((ext_vector_type(2)));

#define NNODES 299593
#define NPAR   37449   // nodes 0..37448 have children
#define NBLK_UPPER 512

static __device__ __forceinline__ unsigned short f2bf(float f) {
  union { float f; unsigned int u; } v; v.f = f;
  unsigned int u = v.u;
  u += 0x7fff + ((u >> 16) & 1);   // RNE
  return (unsigned short)(u >> 16);
}

// pack 2 floats -> 2 bf16 in one dword (a -> low, b -> high)
static __device__ __forceinline__ unsigned int pk2bf(float a, float b) {
#if __has_builtin(__builtin_amdgcn_cvt_pk_bf16_f32)
  typedef __bf16 bf16x2 __attribute__((ext_vector_type(2)));
  union { bf16x2 v; unsigned int u; } c;
  c.v = __builtin_amdgcn_cvt_pk_bf16_f32(a, b);
  return c.u;
#else
  return (unsigned int)f2bf(a) | ((unsigned int)f2bf(b) << 16);
#endif
}

// tanh(x) = 1 - 2/(1+e^{2x})
static __device__ __forceinline__ float fast_tanh(float x) {
  float y = x * 2.885390081777927f;  // 2*log2(e)
#if __has_builtin(__builtin_amdgcn_exp2f)
  float e = __builtin_amdgcn_exp2f(y);
#else
  float e = __builtin_exp2f(y);
#endif
#if __has_builtin(__builtin_amdgcn_rcpf)
  float r = __builtin_amdgcn_rcpf(e + 1.0f);
#else
  float r = 1.0f / (e + 1.0f);
#endif
  return __builtin_fmaf(-2.0f, r, 1.0f);
}

// Swizzle W (128x128 row-major fp32) into B-fragment order for
// v_mfma_f32_16x16x32_bf16: frag f = ((kt*8+nt)*64 + lane)*8 + j
// holds W[kt*32 + (lane>>4)*8 + j][nt*16 + (lane&15)].
// Also converts emb (32000x128 fp32) -> bf16 once, and zeroes the grid
// barrier counters (d_ws is poison-filled by the harness every iteration).
__global__ __launch_bounds__(256) void prep_kernel(
    const float* __restrict__ W_in, const float* __restrict__ U,
    const float* __restrict__ W_out, const float* __restrict__ emb,
    unsigned short* __restrict__ w_sw, unsigned short* __restrict__ emb_bf,
    unsigned int* __restrict__ bar) {
  int t = blockIdx.x * 256 + threadIdx.x;
  if (t < 8)
    __hip_atomic_store(bar + t, 0u, __ATOMIC_RELAXED,
                       __HIP_MEMORY_SCOPE_AGENT);
  if (blockIdx.x < 192) {              // 49152 weight elements
    int f = t;
    int m = f >> 14;
    int r = f & 16383;
    int j = r & 7;
    int lane = (r >> 3) & 63;
    int nt = (r >> 9) & 7;
    int kt = (r >> 12) & 3;
    int k = kt * 32 + ((lane >> 4) * 8) + j;
    int n = nt * 16 + (lane & 15);
    const float* W = (m == 0) ? W_in : (m == 1) ? U : W_out;
    w_sw[f] = f2bf(W[k * 128 + n]);
  } else {                              // 4,096,000 emb elements, 8 per thread
    size_t i = (size_t)(t - 49152) * 8;
    f32x4 v0 = *(const f32x4*)(emb + i);
    f32x4 v1 = *(const f32x4*)(emb + i + 4);
    union { ushort8 s; unsigned int u[4]; } w;
    w.u[0] = pk2bf(v0[0], v0[1]);
    w.u[1] = pk2bf(v0[2], v0[3]);
    w.u[2] = pk2bf(v1[0], v1[1]);
    w.u[3] = pk2bf(v1[2], v1[3]);
    *(ushort8*)(emb_bf + i) = w.s;
  }
}

// load a 16B bf16 A-fragment, zeroed when !nz (per-lane predicate)
static __device__ __forceinline__ bf16x8 ldz(const unsigned short* p, int nz) {
  union { bf16x8 b; unsigned int u[4]; } v;
  v.b = *(const bf16x8*)p;
  if (!nz) { v.u[0] = 0; v.u[1] = 0; v.u[2] = 0; v.u[3] = 0; }
  return v.b;
}

// one K-block (kt) of a 16x128 MFMA row: 8 nt tiles, B frags from
// pre-swizzled global (L1/L2-resident, 32 KB/matrix)
static __device__ __forceinline__ void mfma_row8(f32x4 acc[8], bf16x8 a,
    const unsigned short* __restrict__ bkt, int lane) {
#pragma unroll
  for (int nt = 0; nt < 8; ++nt) {
    bf16x8 b = *(const bf16x8*)(bkt + nt * 512 + lane * 8);
    acc[nt] = __builtin_amdgcn_mfma_f32_16x16x32_bf16(a, b, acc[nt], 0, 0, 0);
  }
}

// CS_ST_AGENT: sc1 agent-scope cs stores when the consumer is in the SAME
// dispatch (per-XCD L2s are not cross-coherent). Reads are always plain
// (see header comment for the safety argument).
template <bool LEAF, bool CS_ST_AGENT>
static __device__ __forceinline__ void tile_body(
    const int* __restrict__ x, const int* __restrict__ mask,
    const unsigned short* __restrict__ emb_bf,
    const float* __restrict__ b_in, const float* __restrict__ b_out,
    const unsigned short* __restrict__ w_sw,
    unsigned short* __restrict__ cs, float* __restrict__ out,
    int e, int row0, unsigned short (*Abuf)[136], int tid) {
  const int lane = tid & 63;
  const int wave = tid >> 6;
  const int coll = lane & 15;
  const int quad = lane >> 4;

  // per-lane A-row (row = coll of this wave's 16-row tile)
  const int garow = row0 + wave * 16 + coll;
  const int valid = garow < e;
  const int m = valid ? mask[garow] : 0;
  const int idx = valid ? x[garow] * m : 0;

  // ---- issue all A-fragment loads up front (hide gather latency) ----
  const unsigned short* arow = emb_bf + (size_t)idx * 128 + quad * 8;
  bf16x8 ea0 = ldz(arow, m);
  bf16x8 ea1 = ldz(arow + 32, m);
  bf16x8 ea2 = ldz(arow + 64, m);
  bf16x8 ea3 = ldz(arow + 96, m);
  bf16x8 ca0, ca1, ca2, ca3;
  if (!LEAF) {
    // childsum row of THIS node, produced by the child level.
    // garow may exceed e for partial tiles but stays < NPAR; ldz zeroes.
    const unsigned short* crow = cs + (size_t)garow * 128 + quad * 8;
    ca0 = ldz(crow, valid);
    ca1 = ldz(crow + 32, valid);
    ca2 = ldz(crow + 64, valid);
    ca3 = ldz(crow + 96, valid);
  }

  f32x4 acc[8];
#pragma unroll
  for (int nt = 0; nt < 8; ++nt) acc[nt] = (f32x4){0.f, 0.f, 0.f, 0.f};

  // ---- GEMM 1: emb @ W_in ----
  mfma_row8(acc, ea0, w_sw, lane);
  mfma_row8(acc, ea1, w_sw + 4096, lane);
  mfma_row8(acc, ea2, w_sw + 8192, lane);
  mfma_row8(acc, ea3, w_sw + 12288, lane);

  // ---- GEMM 2: childsum @ U (accumulates into same acc) ----
  if (!LEAF) {
    mfma_row8(acc, ca0, w_sw + 16384, lane);
    mfma_row8(acc, ca1, w_sw + 20480, lane);
    mfma_row8(acc, ca2, w_sw + 24576, lane);
    mfma_row8(acc, ca3, w_sw + 28672, lane);
  }

  // ---- epilogue 1: + m*b_in, fast tanh; h -> LDS (wave-private) ----
  float binv[8];
#pragma unroll
  for (int nt = 0; nt < 8; ++nt) binv[nt] = b_in[nt * 16 + coll];
#pragma unroll
  for (int r2 = 0; r2 < 4; ++r2) {
    const int rowl = wave * 16 + quad * 4 + r2;  // C layout: row=quad*4+reg
    const int grow = row0 + rowl;
    const float mval = (grow < e) ? (float)mask[grow] : 0.f;
#pragma unroll
    for (int nt = 0; nt < 8; ++nt) {
      float t = acc[nt][r2] + mval * binv[nt];
      Abuf[rowl][nt * 16 + coll] = f2bf(fast_tanh(t));
    }
  }
  __builtin_amdgcn_wave_barrier();

  // ---- childsum production: wave's 16 rows = 2 complete parents ----
  // (row0-1 is divisible by 8 for every level; root tile row0==0 skips)
  if (row0 > 0) {
    const int j = lane >> 5;              // parent 0/1 within wave
    const int c4 = (lane & 31) * 4;       // ushort col 0,4,...,124
    const int childrow0 = row0 + (wave * 2 + j) * 8;
    if (childrow0 < e) {
      const int lr0 = wave * 16 + j * 8;
      f32x2 sA = {0.f, 0.f}, sB = {0.f, 0.f};
#pragma unroll
      for (int r = 0; r < 8; ++r) {       // children ascending: same fp32
        const unsigned int* pr =          // summation order as before
            (const unsigned int*)&Abuf[lr0 + r][c4];
        unsigned int u0 = pr[0], u1 = pr[1];
        union { unsigned int u; float f; } l0, h0, l1, h1;
        l0.u = u0 << 16; h0.u = u0 & 0xffff0000u;
        l1.u = u1 << 16; h1.u = u1 & 0xffff0000u;
        sA += (f32x2){l0.f, h0.f};
        sB += (f32x2){l1.f, h1.f};
      }
      const int p = ((row0 - 1) >> 3) + wave * 2 + j;
      unsigned int wx = pk2bf(sA[0], sA[1]);
      unsigned int wy = pk2bf(sB[0], sB[1]);
      if constexpr (CS_ST_AGENT) {
        unsigned int* q = (unsigned int*)(cs + (size_t)p * 128 + c4);
        __hip_atomic_store(q, wx, __ATOMIC_RELAXED, __HIP_MEMORY_SCOPE_AGENT);
        __hip_atomic_store(q + 1, wy, __ATOMIC_RELAXED,
                           __HIP_MEMORY_SCOPE_AGENT);
      } else {
        uint2v w; w.x = wx; w.y = wy;
        *(uint2v*)(cs + (size_t)p * 128 + c4) = w;
      }
    }
  }

  // ---- GEMM 3: out = h @ W_out + b_out (A frags transposed via LDS) ----
  f32x4 oacc[8];
#pragma unroll
  for (int nt = 0; nt < 8; ++nt) oacc[nt] = (f32x4){0.f, 0.f, 0.f, 0.f};
  const unsigned short* ab = &Abuf[wave * 16][0] + coll * 136 + quad * 8;
#pragma unroll
  for (int kt = 0; kt < 4; ++kt) {
    bf16x8 a = *(const bf16x8*)(ab + kt * 32);
    mfma_row8(oacc, a, w_sw + 32768 + kt * 4096, lane);
  }

  float boutv[8];
#pragma unroll
  for (int nt = 0; nt < 8; ++nt) boutv[nt] = b_out[nt * 16 + coll];
#pragma unroll
  for (int r2 = 0; r2 < 4; ++r2) {
    const int rowl = wave * 16 + quad * 4 + r2;
    const int grow = row0 + rowl;
    if (grow < e) {
#pragma unroll
      for (int nt = 0; nt < 8; ++nt)
        out[(size_t)grow * 128 + nt * 16 + coll] = oacc[nt][r2] + boutv[nt];
    }
  }
}

// Relaxed single-use grid barrier (counters zeroed by prep each launch).
// Safety does not rest on this barrier's ordering: cs stores are sc1
// (coherence-point direct) and __syncthreads' vmcnt(0) drain completes
// them before the increment; readers' plain loads miss L2 (lines never
// cached pre-write this dispatch).
static __device__ __forceinline__ void grid_barrier(unsigned int* ctr,
                                                    int tid) {
  __syncthreads();
  if (tid == 0) {
    __hip_atomic_fetch_add(ctr, 1u, __ATOMIC_RELAXED,
                           __HIP_MEMORY_SCOPE_AGENT);
    while (__hip_atomic_load(ctr, __ATOMIC_RELAXED,
                             __HIP_MEMORY_SCOPE_AGENT) < (unsigned)NBLK_UPPER)
      __builtin_amdgcn_s_sleep(16);
  }
  __syncthreads();
}

// Leaf level: full-TLP regular launch (4096 blocks). cs write consumed next
// dispatch -> plain stores (kernel-end release flushes L2). Plain out
// stores (r1-proven path).
__global__ __launch_bounds__(256) void leaf_kernel(
    const int* __restrict__ x, const int* __restrict__ mask,
    const unsigned short* __restrict__ emb_bf, const float* __restrict__ b_in,
    const float* __restrict__ b_out, const unsigned short* __restrict__ w_sw,
    unsigned short* __restrict__ cs, float* __restrict__ out) {
  __shared__ __align__(16) unsigned short Abuf[64][136];
  tile_body<true, false>(x, mask, emb_bf, b_in, b_out, w_sw, cs, out,
                         299593, 37449 + blockIdx.x * 64, Abuf, threadIdx.x);
}

// Levels 5..0, one REGULAR dispatch, 512 blocks.
// 3 grid barriers (post l5/l4/l3); l2,l1,l0 all run in block 0, chained by
// __syncthreads (same-block sc1-write -> plain-read is safe: vmcnt drain +
// line never cached pre-write).
__global__ __launch_bounds__(256, 4) void upper_kernel(
    const int* __restrict__ x, const int* __restrict__ mask,
    const unsigned short* __restrict__ emb_bf, const float* __restrict__ b_in,
    const float* __restrict__ b_out, const unsigned short* __restrict__ w_sw,
    unsigned short* __restrict__ cs, float* __restrict__ out,
    unsigned int* __restrict__ bar) {
  __shared__ __align__(16) unsigned short Abuf[64][136];
  const int bid = blockIdx.x;
  const int tid = threadIdx.x;

  // l=5: rows 4681..37448, 512 blocks (cs read = leaf's, cross-dispatch)
  tile_body<false, true>(x, mask, emb_bf, b_in, b_out, w_sw, cs, out,
                         37449, 4681 + bid * 64, Abuf, tid);
  grid_barrier(bar + 0, tid);
  // l=4: rows 585..4680, 64 blocks
  if (bid < 64)
    tile_body<false, true>(x, mask, emb_bf, b_in, b_out, w_sw, cs, out,
                           4681, 585 + bid * 64, Abuf, tid);
  grid_barrier(bar + 1, tid);
  // l=3: rows 73..584, 8 blocks
  if (bid < 8)
    tile_body<false, true>(x, mask, emb_bf, b_in, b_out, w_sw, cs, out,
                           585, 73 + bid * 64, Abuf, tid);
  grid_barrier(bar + 2, tid);
  // l=2,1,0: all in block 0, syncthreads-chained
  if (bid == 0) {
    tile_body<false, true>(x, mask, emb_bf, b_in, b_out, w_sw, cs, out,
                           73, 9, Abuf, tid);
    __syncthreads();
    tile_body<false, true>(x, mask, emb_bf, b_in, b_out, w_sw, cs, out,
                           9, 1, Abuf, tid);
    __syncthreads();
    tile_body<false, false>(x, mask, emb_bf, b_in, b_out, w_sw, cs, out,
                            1, 0, Abuf, tid);
  }
}

extern "C" void kernel_launch(void* const* d_in, const int* in_sizes, int n_in,
                              void* d_out, int out_size, void* d_ws,
                              size_t ws_size, hipStream_t stream) {
  const int* x = (const int*)d_in[0];
  const int* mask = (const int*)d_in[1];
  // d_in[2] = children: implied (child rows of i are i*8+1..i*8+8)
  const float* emb = (const float*)d_in[3];
  const float* W_in = (const float*)d_in[4];
  const float* b_in = (const float*)d_in[5];
  const float* U = (const float*)d_in[6];
  const float* W_out = (const float*)d_in[7];
  const float* b_out = (const float*)d_in[8];
  float* out = (float*)d_out;

  // ws layout: emb bf16 [32000*128] | childsum bf16 [NPAR*128] |
  //            w_sw [3*16384] | barrier counters [8 u32]
  unsigned short* emb_bf = (unsigned short*)d_ws;
  unsigned short* cs = emb_bf + (size_t)32000 * 128;
  unsigned short* w_sw = cs + (size_t)NPAR * 128;
  unsigned int* bar = (unsigned int*)(w_sw + 49152);

  prep_kernel<<<2192, 256, 0, stream>>>(W_in, U, W_out, emb, w_sw, emb_bf,
                                        bar);

  // leaf level l=6: rows 37449..299592 -> childsum for parents 4681..37448
  leaf_kernel<<<4096, 256, 0, stream>>>(x, mask, emb_bf, b_in, b_out, w_sw,
                                        cs, out);

  // levels 5..0 in one regular dispatch
  upper_kernel<<<NBLK_UPPER, 256, 0, stream>>>(x, mask, emb_bf, b_in, b_out,
                                               w_sw, cs, out, bar);
}